// Round 7
// baseline (9844.521 us; speedup 1.0000x reference)
//
#include <hip/hip_runtime.h>
#include <hip/hip_fp16.h>
#include <cmath>

typedef _Float16 f16;
typedef _Float16 half8 __attribute__((ext_vector_type(8)));
typedef float f32x4 __attribute__((ext_vector_type(4)));

#define P_WG   38          // workgroups per direction (16 hidden units each; last has 8)
#define GRID_MAIN (2*P_WG) // 76
#define G      8           // XZ lookahead distance
#define RING   9           // XZ ring slots (G+1)

#define X16_ELEMS  (64u*512u*320u)            // 10,485,760 f16 per plane
#define BPK_TERM   (2u*76u*2u*30u*64u*8u)     // 4,669,440 f16 (one term plane, 76 col-octets)
#define HBUF_F16   (2u*2u*64u*640u)           // dirs*bufs*rows*cols f16
#define HBUF_WORDS (HBUF_F16/2u)              // 81,920 u32
#define FLAG_WORDS 64u                        // 2 dirs x 32 u32 (ctr at dir*32)

// ---------------- prep: rebuild all workspace state every launch ----------------
__global__ void lstm_prep(const float* __restrict__ x,
                          const float* __restrict__ Wf, const float* __restrict__ Uf,
                          const float* __restrict__ Wb, const float* __restrict__ Ub,
                          const int* __restrict__ len,
                          f16* __restrict__ x16h, f16* __restrict__ x16l,
                          f16* __restrict__ Bpk,
                          unsigned* __restrict__ hbw, unsigned* __restrict__ flags,
                          int* __restrict__ maxT, float* __restrict__ outp)
{
    const unsigned total = X16_ELEMS + BPK_TERM + HBUF_WORDS + FLAG_WORDS + 2u;
    for (unsigned e = blockIdx.x * blockDim.x + threadIdx.x; e < total;
         e += gridDim.x * blockDim.x) {
        if (e < X16_ELEMS) {
            unsigned k = e % 320u, r = e / 320u;   // r = b*512 + t
            float v = (k < 300u) ? x[r * 300u + k] : 0.0f;
            f16 hi = (f16)v;
            x16h[e] = hi;
            x16l[e] = (f16)((v - (float)hi) * 2048.0f);
        } else if (e < X16_ELEMS + BPK_TERM) {
            unsigned i = e - X16_ELEMS;
            // layout: [dir][p76][term][nt2][kt30][lane][8]; fills term=0 and term=1
            unsigned j    = i & 7u,  r1 = i >> 3;
            unsigned lane = r1 & 63u, r2 = r1 >> 6;
            unsigned kt   = r2 % 30u, r3 = r2 / 30u;
            unsigned nt   = r3 & 1u,  r4 = r3 >> 1;
            unsigned p    = r4 % 76u, dw = r4 / 76u;
            unsigned k = kt * 32u + (lane >> 4) * 8u + j;     // B[k][n], k-octet per quad
            unsigned n = nt * 16u + (lane & 15u);             // n = gatepair*8 + jj
            float v = 0.0f;
            if (p < 75u) {                                    // p=75 is zero pad (600=75*8)
                unsigned c = (n >> 3) * 600u + p * 8u + (n & 7u); // column in [0,2400)
                if (k < 300u)                    v = (dw ? Wb : Wf)[k * 2400u + c];
                else if (k >= 320u && k < 920u)  v = (dw ? Ub : Uf)[(k - 320u) * 2400u + c];
            }
            f16 hi = (f16)v;
            unsigned base = (((((dw * 76u + p) * 2u + 0u) * 2u + nt) * 30u + kt) * 64u + lane) * 8u + j;
            Bpk[base]          = hi;
            Bpk[base + 30720u] = (f16)((v - (float)hi) * 2048.0f); // lo pre-scaled by 2^11
        } else if (e < X16_ELEMS + BPK_TERM + HBUF_WORDS) {
            hbw[e - X16_ELEMS - BPK_TERM] = 0u;   // zero h ping-pong buffers, both dirs
        } else if (e < X16_ELEMS + BPK_TERM + HBUF_WORDS + FLAG_WORDS) {
            flags[e - (X16_ELEMS + BPK_TERM + HBUF_WORDS)] = 0u;
        } else {
            unsigned q = e - (X16_ELEMS + BPK_TERM + HBUF_WORDS + FLAG_WORDS);
            if (q == 0u) {
                int m = 1;
                for (int b = 0; b < 64; ++b) { int L = len[b]; m = (L > m) ? L : m; }
                *maxT = m;
            } else {
                outp[0] = 1000.0f;   // sentinel: lstm_main always overwrites out[0]
            }
        }
    }
}

// MALL-direct 16B load as 2x8B agent-scope atomic loads (bypass L1/L2 -> always fresh)
__device__ __forceinline__ half8 ld_h8_mall(const f16* p) {
    union { unsigned long long u[2]; half8 h; } x;
    x.u[0] = __hip_atomic_load((const unsigned long long*)p,     __ATOMIC_RELAXED, __HIP_MEMORY_SCOPE_AGENT);
    x.u[1] = __hip_atomic_load((const unsigned long long*)p + 1, __ATOMIC_RELAXED, __HIP_MEMORY_SCOPE_AGENT);
    return x.h;
}

// ---------------- main persistent recurrent kernel ----------------
__global__ __launch_bounds__(256, 1)
void lstm_main(const f16* __restrict__ x16h, const f16* __restrict__ x16l,
               const f16* __restrict__ Bpk,
               f16* __restrict__ hbuf, float* __restrict__ xz,
               unsigned* flags, const int* __restrict__ maxT,
               const int* __restrict__ len,
               const float* __restrict__ bfv, const float* __restrict__ bbv,
               float* __restrict__ out)
{
    __shared__ f32x4 obox[4][4][4][64];   // [src_wave][mt][ntx][lane] : 64 KB merge buffer
    __shared__ f16 hstage[64][16];        // h transpose staging: 2 KB

    const int tid  = threadIdx.x;
    const int wave = tid >> 6, lane = tid & 63;
    const int quad = lane >> 4, l15 = lane & 15;
    const int dir  = blockIdx.x & 1, p = blockIdx.x >> 1;
    const int wg   = blockIdx.x;

    // ---- resident h-part B fragments (hi term only): wave owns 5 kt in [10,30) ----
    const int s0 = (wave < 2) ? 3 : 2;    // kt = wave + 4*(s0+sp), sp=0..4
    half8 Bh[5][4];
#pragma unroll
    for (int sp = 0; sp < 5; ++sp) {
        int kt = wave + 4 * (s0 + sp);
#pragma unroll
        for (int ntx = 0; ntx < 4; ++ntx) {
            int p2 = 2 * p + (ntx >> 1);
            Bh[sp][ntx] = *(const half8*)(Bpk +
                (((((unsigned)(dir * 76 + p2) * 2 + 0) * 2 + (ntx & 1)) * 30 + kt) * 64 + lane) * 8);
        }
    }
    const float* bias = dir ? bbv : bfv;
    float bz[4];
#pragma unroll
    for (int ntx = 0; ntx < 4; ++ntx) {
        int p2 = 2 * p + (ntx >> 1);
        bz[ntx] = (p2 < 75) ?
            bias[((ntx & 1) * 2 + (l15 >> 3)) * 600 + p2 * 8 + (l15 & 7)] : 0.0f;
    }

    const int Lw = len[wave * 16 + l15];   // burst A rows (this wave's 16 batch rows)
    int Lr[4];
#pragma unroll
    for (int r = 0; r < 4; ++r) Lr[r] = len[wave * 16 + quad * 4 + r]; // epilogue rows

    f16* hb0 = hbuf + dir * (2 * 64 * 640);
    unsigned* myctr = flags + dir * 32;
    float* myxz = xz + (size_t)wg * (RING * 64 * 64);
    float cst[2][4] = {{0,0,0,0},{0,0,0,0}}, sum[2][4] = {{0,0,0,0},{0,0,0,0}};
    const int T = *maxT;
    const unsigned bpk_dirp = (unsigned)(dir * 76 + 2 * p);

    // burst: XZ(tt) = x_tt * W + b for this wave's 16 batch rows, all 4 ntx cols
    auto burst = [&](int slot, int tt) {
        int tx = tt;
        if (dir) tx = (tt < Lw) ? (Lw - 1 - tt) : tt;   // reverse_sequence
        unsigned arow = ((unsigned)(wave * 16 + l15) * 512u + (unsigned)tx) * 320u + quad * 8;
        f32x4 aH[4], aM[4];
#pragma unroll
        for (int ntx = 0; ntx < 4; ++ntx) {
            aH[ntx] = f32x4{0.f, 0.f, 0.f, 0.f};
            aM[ntx] = f32x4{0.f, 0.f, 0.f, 0.f};
        }
#pragma unroll
        for (int kt = 0; kt < 10; ++kt) {
            half8 Ah = *(const half8*)(x16h + arow + kt * 32);
            half8 Al = *(const half8*)(x16l + arow + kt * 32);
#pragma unroll
            for (int ntx = 0; ntx < 4; ++ntx) {
                const f16* bb = Bpk +
                    ((((bpk_dirp + (ntx >> 1)) * 2u + 0u) * 2u + (ntx & 1)) * 30u + kt) * 512u + lane * 8;
                half8 Bhi = *(const half8*)bb;
                half8 Blo = *(const half8*)(bb + 30720u);
                aH[ntx] = __builtin_amdgcn_mfma_f32_16x16x32_f16(Ah, Bhi, aH[ntx], 0, 0, 0);
                aM[ntx] = __builtin_amdgcn_mfma_f32_16x16x32_f16(Ah, Blo, aM[ntx], 0, 0, 0);
                aM[ntx] = __builtin_amdgcn_mfma_f32_16x16x32_f16(Al, Bhi, aM[ntx], 0, 0, 0);
            }
        }
#pragma unroll
        for (int ntx = 0; ntx < 4; ++ntx)
#pragma unroll
            for (int r = 0; r < 4; ++r)
                myxz[(unsigned)(slot * 64 + wave * 16 + quad * 4 + r) * 64u + ntx * 16 + l15] =
                    aH[ntx][r] + aM[ntx][r] * (1.0f / 2048.0f) + bz[ntx];
    };

    // ---- initial fill: XZ ring slots 0..G-1 (each wave its own rows; no barrier needed) ----
    for (int g = 0; g < G; ++g) burst(g, g);

    for (int t = 0; t < T; ++t) {
        // ---- pipelined burst for step t+G (overlaps the notify chain) ----
        if (t + G < T) burst((t + G) % RING, t + G);

        // ---- preload this step's XZ into registers (WG-local, L1-warm) ----
        float zz[4][4];
        {
            unsigned rbase = (unsigned)((t % RING) * 64 + wave * 16 + quad * 4) * 64u;
#pragma unroll
            for (int ntx = 0; ntx < 4; ++ntx)
#pragma unroll
                for (int r = 0; r < 4; ++r)
                    zz[ntx][r] = myxz[rbase + r * 64 + ntx * 16 + l15];
        }

        const f16* hcur = hb0 + (t & 1) * (64 * 640);
        f16*       hnxt = hb0 + ((t + 1) & 1) * (64 * 640);

        // ---- wait: wave 0 polls the single per-dir counter; barrier releases WG ----
        if (t > 0) {
            if (wave == 0) {
                const unsigned tgt = (unsigned)(P_WG * t);
                for (;;) {
                    unsigned v = __hip_atomic_load(myctr, __ATOMIC_RELAXED, __HIP_MEMORY_SCOPE_AGENT);
                    if (v >= tgt) break;
                    __builtin_amdgcn_s_sleep(1);
                }
                __builtin_amdgcn_fence(__ATOMIC_ACQUIRE, "workgroup"); // order only; no cache inv
            }
        }
        __syncthreads();   // B1: release all waves after the poll

        // ---- h-part MFMAs; h read MALL-direct (fresh without cache inv) ----
        f32x4 acc[4][4];
#pragma unroll
        for (int mt = 0; mt < 4; ++mt)
#pragma unroll
            for (int ntx = 0; ntx < 4; ++ntx)
                acc[mt][ntx] = f32x4{0.f, 0.f, 0.f, 0.f};
#pragma unroll
        for (int sp = 0; sp < 5; ++sp) {
            int kt = wave + 4 * (s0 + sp);
#pragma unroll
            for (int mt = 0; mt < 4; ++mt) {
                half8 Ah = ld_h8_mall(hcur + (unsigned)(mt * 16 + l15) * 640u + (kt * 32 - 320) + quad * 8);
#pragma unroll
                for (int ntx = 0; ntx < 4; ++ntx)
                    acc[mt][ntx] = __builtin_amdgcn_mfma_f32_16x16x32_f16(Ah, Bh[sp][ntx], acc[mt][ntx], 0, 0, 0);
            }
        }

        // ---- all-to-all K-merge through LDS ----
#pragma unroll
        for (int mt = 0; mt < 4; ++mt)
#pragma unroll
            for (int ntx = 0; ntx < 4; ++ntx)
                obox[wave][mt][ntx][lane] = acc[mt][ntx];
        __syncthreads();   // B2: obox write -> read
        f32x4 z[4];
#pragma unroll
        for (int ntx = 0; ntx < 4; ++ntx) {
            z[ntx] = obox[0][wave][ntx][lane] + obox[1][wave][ntx][lane]
                   + obox[2][wave][ntx][lane] + obox[3][wave][ntx][lane];
            z[ntx] += f32x4{zz[ntx][0], zz[ntx][1], zz[ntx][2], zz[ntx][3]};
        }

        // ---- epilogue: this wave owns batch rows wave*16..wave*16+15, 16 hidden cols ----
#pragma unroll
        for (int o = 0; o < 2; ++o) {
#pragma unroll
            for (int r = 0; r < 4; ++r) {
                float zi = z[o * 2][r],     zg = z[o * 2 + 1][r];
                float zf = __shfl_xor(z[o * 2][r], 8, 64);      // f gate 8 lanes over
                float zo = __shfl_xor(z[o * 2 + 1][r], 8, 64);
                if (l15 < 8) {
                    float ig = 1.0f / (1.0f + __expf(-zi));
                    float fg = 1.0f / (1.0f + __expf(-zf));
                    float gg = tanhf(zg);
                    float og = 1.0f / (1.0f + __expf(-zo));
                    float c  = fg * cst[o][r] + ig * gg;
                    cst[o][r] = c;
                    float h = og * tanhf(c);
                    if (t < Lr[r]) sum[o][r] += h;
                    hstage[wave * 16 + quad * 4 + r][o * 8 + l15] = (f16)h;
                }
            }
        }
        __syncthreads();   // B3: hstage ready; waves 1-3 run ahead to next burst

        // ---- wave 0 publishes h (2 KB) + release-add (orders after own stores) ----
        if (wave == 0) {
#pragma unroll
            for (int q = 0; q < 4; ++q) {
                unsigned long long v = ((const unsigned long long*)&hstage[lane][0])[q];
                __hip_atomic_store(
                    (unsigned long long*)(hnxt + (unsigned)lane * 640u + p * 16 + q * 4),
                    v, __ATOMIC_RELAXED, __HIP_MEMORY_SCOPE_AGENT);
            }
            if (lane == 0)
                __hip_atomic_fetch_add(myctr, 1u, __ATOMIC_RELEASE, __HIP_MEMORY_SCOPE_AGENT);
        }
    }

    // ---- output: mean over T with masking (sum already masked) ----
#pragma unroll
    for (int o = 0; o < 2; ++o) {
        int colb = p * 16 + o * 8;
        if (l15 < 8 && colb < 600) {
#pragma unroll
            for (int r = 0; r < 4; ++r)
                out[(wave * 16 + quad * 4 + r) * 1200 + dir * 600 + colb + l15] =
                    sum[o][r] * (1.0f / 512.0f);
        }
    }
}

// ---------------- launcher ----------------
extern "C" void kernel_launch(void* const* d_in, const int* in_sizes, int n_in,
                              void* d_out, int out_size, void* d_ws, size_t ws_size,
                              hipStream_t stream) {
    const float* x   = (const float*)d_in[0];
    const int*   len = (const int*)  d_in[1];
    const float* Wf  = (const float*)d_in[3];
    const float* Uf  = (const float*)d_in[4];
    const float* bfv = (const float*)d_in[5];
    const float* Wb  = (const float*)d_in[6];
    const float* Ub  = (const float*)d_in[7];
    const float* bbv = (const float*)d_in[8];
    float* outp = (float*)d_out;

    char* w = (char*)d_ws;
    f16*      x16hp = (f16*)w;                         // 20,971,520 B
    f16*      x16lp = (f16*)(w + 20971520);            // 20,971,520 B
    f16*      bpkp  = (f16*)(w + 41943040);            // 18,677,760 B
    f16*      hbufp = (f16*)(w + 60620800);            //    327,680 B
    float*    xzp   = (float*)(w + 60948480);          // 76*9*64*64*4 = 11,206,656 B
    unsigned* flagp = (unsigned*)(w + 72155136);       //        256 B
    int*      maxtp = (int*)(w + 72155392);

    hipLaunchKernelGGL(lstm_prep, dim3(1024), dim3(256), 0, stream,
                       x, Wf, Uf, Wb, Ub, len,
                       x16hp, x16lp, bpkp, (unsigned*)hbufp, flagp, maxtp, outp);

    hipLaunchKernelGGL(lstm_main, dim3(GRID_MAIN), dim3(256), 0, stream,
                       x16hp, x16lp, bpkp, hbufp, xzp, flagp, maxtp, len, bfv, bbv, outp);
}

// Round 8
// 6980.869 us; speedup vs baseline: 1.4102x; 1.4102x over previous
//
#include <hip/hip_runtime.h>
#include <hip/hip_fp16.h>
#include <cmath>

typedef _Float16 f16;
typedef _Float16 half8 __attribute__((ext_vector_type(8)));
typedef float f32x4 __attribute__((ext_vector_type(4)));

#define P_WG   75          // workgroups per direction (8 hidden units each)
#define GRID_MAIN (2*P_WG) // 150
#define G      12          // XZ lookahead distance
#define RING   13          // XZ ring slots (G+1)

#define X16_ELEMS  (64u*512u*320u)            // 10,485,760 f16 per plane
#define BPK_HALF   (2u*75u*2u*30u*64u*8u)     // 4,608,000 f16 (one term plane)
#define HBUF_F16   (2u*2u*64u*640u)           // dirs*bufs*rows*cols f16
#define HBUF_WORDS (HBUF_F16/2u)              // 81,920 u32
#define FLAG_WORDS 64u                        // 2 dirs x 32 u32 (ctr at dir*32)

// ---------------- prep: rebuild all workspace state every launch ----------------
__global__ void lstm_prep(const float* __restrict__ x,
                          const float* __restrict__ Wf, const float* __restrict__ Uf,
                          const float* __restrict__ Wb, const float* __restrict__ Ub,
                          const int* __restrict__ len,
                          f16* __restrict__ x16h, f16* __restrict__ x16l,
                          f16* __restrict__ Bpk,
                          unsigned* __restrict__ hbw, unsigned* __restrict__ flags,
                          int* __restrict__ maxT, float* __restrict__ outp)
{
    const unsigned total = X16_ELEMS + BPK_HALF + HBUF_WORDS + FLAG_WORDS + 2u;
    for (unsigned e = blockIdx.x * blockDim.x + threadIdx.x; e < total;
         e += gridDim.x * blockDim.x) {
        if (e < X16_ELEMS) {
            unsigned k = e % 320u, r = e / 320u;   // r = b*512 + t
            float v = (k < 300u) ? x[r * 300u + k] : 0.0f;
            f16 hi = (f16)v;
            x16h[e] = hi;
            x16l[e] = (f16)((v - (float)hi) * 2048.0f);
        } else if (e < X16_ELEMS + BPK_HALF) {
            unsigned i = e - X16_ELEMS;
            // layout: [dir][p][term][nt][kt][lane][8]; fills term=0 and term=1
            unsigned j    = i & 7u,  r1 = i >> 3;
            unsigned lane = r1 & 63u, r2 = r1 >> 6;
            unsigned kt   = r2 % 30u, r3 = r2 / 30u;
            unsigned nt   = r3 & 1u,  r4 = r3 >> 1;
            unsigned p    = r4 % 75u, dw = r4 / 75u;
            unsigned k = kt * 32u + (lane >> 4) * 8u + j;     // B[k][n], k-octet per quad
            unsigned n = nt * 16u + (lane & 15u);             // n = gate*8 + jj
            unsigned c = (n >> 3) * 600u + p * 8u + (n & 7u); // source column in [0,2400)
            float v = 0.0f;
            if (k < 300u)                    v = (dw ? Wb : Wf)[k * 2400u + c];
            else if (k >= 320u && k < 920u)  v = (dw ? Ub : Uf)[(k - 320u) * 2400u + c];
            f16 hi = (f16)v;
            unsigned base = (((((dw * 75u + p) * 2u + 0u) * 2u + nt) * 30u + kt) * 64u + lane) * 8u + j;
            Bpk[base]          = hi;
            Bpk[base + 30720u] = (f16)((v - (float)hi) * 2048.0f); // lo pre-scaled by 2^11
        } else if (e < X16_ELEMS + BPK_HALF + HBUF_WORDS) {
            hbw[e - X16_ELEMS - BPK_HALF] = 0u;   // zero h ping-pong buffers, both dirs
        } else if (e < X16_ELEMS + BPK_HALF + HBUF_WORDS + FLAG_WORDS) {
            flags[e - (X16_ELEMS + BPK_HALF + HBUF_WORDS)] = 0u;
        } else {
            unsigned q = e - (X16_ELEMS + BPK_HALF + HBUF_WORDS + FLAG_WORDS);
            if (q == 0u) {
                int m = 1;
                for (int b = 0; b < 64; ++b) { int L = len[b]; m = (L > m) ? L : m; }
                *maxT = m;
            } else {
                outp[0] = 1000.0f;   // sentinel: lstm_main always overwrites out[0]
            }
        }
    }
}

// MALL-direct 16B load as 2x8B agent-scope atomic loads (bypass L1/L2 -> always fresh)
__device__ __forceinline__ half8 ld_h8_mall(const f16* p) {
    union { unsigned long long u[2]; half8 h; } x;
    x.u[0] = __hip_atomic_load((const unsigned long long*)p,     __ATOMIC_RELAXED, __HIP_MEMORY_SCOPE_AGENT);
    x.u[1] = __hip_atomic_load((const unsigned long long*)p + 1, __ATOMIC_RELAXED, __HIP_MEMORY_SCOPE_AGENT);
    return x.h;
}

// ---------------- main persistent recurrent kernel ----------------
__global__ __launch_bounds__(256, 1)
void lstm_main(const f16* __restrict__ x16h, const f16* __restrict__ x16l,
               const f16* __restrict__ Bpk,
               f16* __restrict__ hbuf, float* __restrict__ xz,
               unsigned* flags, const int* __restrict__ maxT,
               const int* __restrict__ len,
               const float* __restrict__ bfv, const float* __restrict__ bbv,
               float* __restrict__ out)
{
    __shared__ f32x4 obox[4][4][2][64];   // [src_wave][mt][nt][lane] : 32 KB merge buffer
    __shared__ f16 hstage[64][8];         // h transpose staging: 1 KB

    const int tid  = threadIdx.x;
    const int wave = tid >> 6, lane = tid & 63;
    const int quad = lane >> 4, l15 = lane & 15;
    const int dir  = blockIdx.x & 1, p = blockIdx.x >> 1;
    const int pc   = p * 8;
    const int wg   = blockIdx.x;

    // ---- resident h-part B fragments (hi term ONLY — U f16 quant is enough,
    //      verified R7: absmax unchanged): wave owns 5 kt in [10,30) ----
    const int s0 = (wave < 2) ? 3 : 2;    // kt = wave + 4*(s0+sp), sp=0..4
    half8 Bh[5][2];
#pragma unroll
    for (int sp = 0; sp < 5; ++sp) {
        int kt = wave + 4 * (s0 + sp);
#pragma unroll
        for (int nt = 0; nt < 2; ++nt)
            Bh[sp][nt] = *(const half8*)(Bpk +
                (((((unsigned)(dir * 75 + p) * 2 + 0) * 2 + nt) * 30 + kt) * 64 + lane) * 8);
    }
    const float* bias = dir ? bbv : bfv;
    const float b0 = bias[((l15 >> 3)    ) * 600 + pc + (l15 & 7)];  // gates i|f tile
    const float b1 = bias[((l15 >> 3) + 2) * 600 + pc + (l15 & 7)];  // gates g|o tile

    int Lm[4], Lr[4];
#pragma unroll
    for (int mt = 0; mt < 4; ++mt) Lm[mt] = len[mt * 16 + l15];        // initial-burst A rows
    const int Lw = len[wave * 16 + l15];                               // steady-burst A rows
#pragma unroll
    for (int r = 0; r < 4; ++r)   Lr[r]  = len[wave * 16 + quad * 4 + r]; // epilogue rows

    f16* hb0 = hbuf + dir * (2 * 64 * 640);
    unsigned* myctr = flags + dir * 32;
    float* myxz = xz + (size_t)wg * (RING * 64 * 32);
    float cst[4] = {0, 0, 0, 0}, sum[4] = {0, 0, 0, 0};
    const int T = *maxT;
    const unsigned bpk_base = (unsigned)(dir * 75 + p) * 4u * 30u * 512u;  // [dir][p] block, elems

    // ---- initial burst: fill XZ ring slots 0..G-1 (wave g-split, full K) ----
#pragma unroll
    for (int jc = 0; jc < 3; ++jc) {
        int g = wave * 3 + jc;
        int tt = (g < 512) ? g : 511;
        unsigned arow[4];
#pragma unroll
        for (int mt = 0; mt < 4; ++mt) {
            int tx = tt;
            if (dir) tx = (tt < Lm[mt]) ? (Lm[mt] - 1 - tt) : tt;  // reverse_sequence
            arow[mt] = ((unsigned)(mt * 16 + l15) * 512u + (unsigned)tx) * 320u + quad * 8;
        }
        f32x4 aH[4][2], aM[4][2];
#pragma unroll
        for (int mt = 0; mt < 4; ++mt)
#pragma unroll
            for (int nt = 0; nt < 2; ++nt) {
                aH[mt][nt] = f32x4{0.f, 0.f, 0.f, 0.f};
                aM[mt][nt] = f32x4{0.f, 0.f, 0.f, 0.f};
            }
#pragma unroll
        for (int kt = 0; kt < 10; ++kt) {
            const f16* bb = Bpk + bpk_base + kt * 512u + lane * 8;
            half8 B00 = *(const half8*)(bb);
            half8 B01 = *(const half8*)(bb + 15360);
            half8 B10 = *(const half8*)(bb + 30720);
            half8 B11 = *(const half8*)(bb + 46080);
#pragma unroll
            for (int mt = 0; mt < 4; ++mt) {
                half8 Ah = *(const half8*)(x16h + arow[mt] + kt * 32);
                half8 Al = *(const half8*)(x16l + arow[mt] + kt * 32);
                aH[mt][0] = __builtin_amdgcn_mfma_f32_16x16x32_f16(Ah, B00, aH[mt][0], 0, 0, 0);
                aM[mt][0] = __builtin_amdgcn_mfma_f32_16x16x32_f16(Ah, B10, aM[mt][0], 0, 0, 0);
                aM[mt][0] = __builtin_amdgcn_mfma_f32_16x16x32_f16(Al, B00, aM[mt][0], 0, 0, 0);
                aH[mt][1] = __builtin_amdgcn_mfma_f32_16x16x32_f16(Ah, B01, aH[mt][1], 0, 0, 0);
                aM[mt][1] = __builtin_amdgcn_mfma_f32_16x16x32_f16(Ah, B11, aM[mt][1], 0, 0, 0);
                aM[mt][1] = __builtin_amdgcn_mfma_f32_16x16x32_f16(Al, B01, aM[mt][1], 0, 0, 0);
            }
        }
#pragma unroll
        for (int mt = 0; mt < 4; ++mt)
#pragma unroll
            for (int r = 0; r < 4; ++r) {
                unsigned rowi = (unsigned)(g * 64 + mt * 16 + quad * 4 + r) * 32u;
                myxz[rowi + l15]      = aH[mt][0][r] + aM[mt][0][r] * (1.0f / 2048.0f) + b0;
                myxz[rowi + 16 + l15] = aH[mt][1][r] + aM[mt][1][r] * (1.0f / 2048.0f) + b1;
            }
    }
    __syncthreads();   // XZ slots 0..G-1 visible WG-wide (same CU: L1-coherent)

    for (int t = 0; t < T; ++t) {
        // ---- pipelined burst for step t+G (overlaps the notify chain) ----
        int tf = t + G;
        if (tf < T) {
            int tx = tf;
            if (dir) tx = (tf < Lw) ? (Lw - 1 - tf) : tf;
            unsigned arow = ((unsigned)(wave * 16 + l15) * 512u + (unsigned)tx) * 320u + quad * 8;
            f32x4 aH[2], aM[2];
            aH[0] = f32x4{0.f, 0.f, 0.f, 0.f}; aM[0] = f32x4{0.f, 0.f, 0.f, 0.f};
            aH[1] = f32x4{0.f, 0.f, 0.f, 0.f}; aM[1] = f32x4{0.f, 0.f, 0.f, 0.f};
#pragma unroll
            for (int kt = 0; kt < 10; ++kt) {
                const f16* bb = Bpk + bpk_base + kt * 512u + lane * 8;
                half8 B00 = *(const half8*)(bb);
                half8 B01 = *(const half8*)(bb + 15360);
                half8 B10 = *(const half8*)(bb + 30720);
                half8 B11 = *(const half8*)(bb + 46080);
                half8 Ah = *(const half8*)(x16h + arow + kt * 32);
                half8 Al = *(const half8*)(x16l + arow + kt * 32);
                aH[0] = __builtin_amdgcn_mfma_f32_16x16x32_f16(Ah, B00, aH[0], 0, 0, 0);
                aM[0] = __builtin_amdgcn_mfma_f32_16x16x32_f16(Ah, B10, aM[0], 0, 0, 0);
                aM[0] = __builtin_amdgcn_mfma_f32_16x16x32_f16(Al, B00, aM[0], 0, 0, 0);
                aH[1] = __builtin_amdgcn_mfma_f32_16x16x32_f16(Ah, B01, aH[1], 0, 0, 0);
                aM[1] = __builtin_amdgcn_mfma_f32_16x16x32_f16(Ah, B11, aM[1], 0, 0, 0);
                aM[1] = __builtin_amdgcn_mfma_f32_16x16x32_f16(Al, B01, aM[1], 0, 0, 0);
            }
            int slot = tf % RING;
#pragma unroll
            for (int r = 0; r < 4; ++r) {
                unsigned rowi = (unsigned)(slot * 64 + wave * 16 + quad * 4 + r) * 32u;
                myxz[rowi + l15]      = aH[0][r] + aM[0][r] * (1.0f / 2048.0f) + b0;
                myxz[rowi + 16 + l15] = aH[1][r] + aM[1][r] * (1.0f / 2048.0f) + b1;
            }
        }

        // ---- preload this step's XZ into registers (WG-local, L1-warm) ----
        float z0p[4], z1p[4];
        {
            int slot = t % RING;
            unsigned rbase = (unsigned)(slot * 64 + wave * 16 + quad * 4) * 32u;
#pragma unroll
            for (int r = 0; r < 4; ++r) {
                z0p[r] = myxz[rbase + r * 32 + l15];
                z1p[r] = myxz[rbase + r * 32 + 16 + l15];
            }
        }

        const f16* hcur = hb0 + (t & 1) * (64 * 640);
        f16*       hnxt = hb0 + ((t + 1) & 1) * (64 * 640);

        // ---- wait (R7 scheme, verified outlier-free): wave 0 polls the single
        //      per-dir counter; barrier releases the WG ----
        if (t > 0 && wave == 0) {
            const unsigned tgt = (unsigned)(P_WG * t);
            for (;;) {
                unsigned v = __hip_atomic_load(myctr, __ATOMIC_RELAXED, __HIP_MEMORY_SCOPE_AGENT);
                if (v >= tgt) break;
                __builtin_amdgcn_s_sleep(1);
            }
            __builtin_amdgcn_fence(__ATOMIC_ACQUIRE, "workgroup"); // order only; no cache inv
        }
        __syncthreads();   // B1: release all waves after the poll

        // ---- h-part MFMAs (hi U only); h read MALL-direct (fresh, no cache inv) ----
        f32x4 acc[4][2];
#pragma unroll
        for (int mt = 0; mt < 4; ++mt)
#pragma unroll
            for (int nt = 0; nt < 2; ++nt)
                acc[mt][nt] = f32x4{0.f, 0.f, 0.f, 0.f};
#pragma unroll
        for (int sp = 0; sp < 5; ++sp) {
            int kt = wave + 4 * (s0 + sp);
#pragma unroll
            for (int mt = 0; mt < 4; ++mt) {
                half8 Ah = ld_h8_mall(hcur + (unsigned)(mt * 16 + l15) * 640u + (kt * 32 - 320) + quad * 8);
#pragma unroll
                for (int nt = 0; nt < 2; ++nt)
                    acc[mt][nt] = __builtin_amdgcn_mfma_f32_16x16x32_f16(Ah, Bh[sp][nt], acc[mt][nt], 0, 0, 0);
            }
        }

        // ---- all-to-all K-merge through LDS ----
#pragma unroll
        for (int mt = 0; mt < 4; ++mt)
#pragma unroll
            for (int nt = 0; nt < 2; ++nt)
                obox[wave][mt][nt][lane] = acc[mt][nt];
        __syncthreads();   // B2: obox write -> read
        f32x4 z0 = obox[0][wave][0][lane] + obox[1][wave][0][lane]
                 + obox[2][wave][0][lane] + obox[3][wave][0][lane];
        f32x4 z1 = obox[0][wave][1][lane] + obox[1][wave][1][lane]
                 + obox[2][wave][1][lane] + obox[3][wave][1][lane];
        z0 += f32x4{z0p[0], z0p[1], z0p[2], z0p[3]};
        z1 += f32x4{z1p[0], z1p[1], z1p[2], z1p[3]};

        // ---- epilogue: this wave owns batch rows wave*16 .. wave*16+15 ----
#pragma unroll
        for (int r = 0; r < 4; ++r) {
            float zi = z0[r], zg = z1[r];
            float zf = __shfl_xor(z0[r], 8, 64);  // f gate lives 8 lanes over
            float zo = __shfl_xor(z1[r], 8, 64);
            if (l15 < 8) {
                float ig = 1.0f / (1.0f + __expf(-zi));
                float fg = 1.0f / (1.0f + __expf(-zf));
                float gg = tanhf(zg);
                float og = 1.0f / (1.0f + __expf(-zo));
                float c  = fg * cst[r] + ig * gg;
                cst[r] = c;
                float h = og * tanhf(c);
                if (t < Lr[r]) sum[r] += h;
                hstage[wave * 16 + quad * 4 + r][l15] = (f16)h;
            }
        }
        __syncthreads();   // B3: hstage ready; waves 1-3 run ahead to next burst

        // ---- wave 0 publishes h (1 KB: 64 rows x 16B) + release-add; the
        //      release fence orders its OWN stores (vmcnt drain) before the add ----
        if (wave == 0) {
            unsigned long long v0 = ((const unsigned long long*)&hstage[lane][0])[0];
            unsigned long long v1 = ((const unsigned long long*)&hstage[lane][0])[1];
            unsigned long long* dst = (unsigned long long*)(hnxt + (unsigned)lane * 640u + pc);
            __hip_atomic_store(dst,     v0, __ATOMIC_RELAXED, __HIP_MEMORY_SCOPE_AGENT);
            __hip_atomic_store(dst + 1, v1, __ATOMIC_RELAXED, __HIP_MEMORY_SCOPE_AGENT);
            if (lane == 0)
                __hip_atomic_fetch_add(myctr, 1u, __ATOMIC_RELEASE, __HIP_MEMORY_SCOPE_AGENT);
        }
    }

    // ---- output: masked mean over the sequence ----
    if (l15 < 8) {
#pragma unroll
        for (int r = 0; r < 4; ++r)
            out[(wave * 16 + quad * 4 + r) * 1200 + dir * 600 + pc + l15] =
                sum[r] * (1.0f / 512.0f);
    }
}

// ---------------- launcher ----------------
extern "C" void kernel_launch(void* const* d_in, const int* in_sizes, int n_in,
                              void* d_out, int out_size, void* d_ws, size_t ws_size,
                              hipStream_t stream) {
    const float* x   = (const float*)d_in[0];
    const int*   len = (const int*)  d_in[1];
    const float* Wf  = (const float*)d_in[3];
    const float* Uf  = (const float*)d_in[4];
    const float* bfv = (const float*)d_in[5];
    const float* Wb  = (const float*)d_in[6];
    const float* Ub  = (const float*)d_in[7];
    const float* bbv = (const float*)d_in[8];
    float* outp = (float*)d_out;

    char* w = (char*)d_ws;
    f16*      x16hp = (f16*)w;                         // 20,971,520 B
    f16*      x16lp = (f16*)(w + 20971520);            // 20,971,520 B
    f16*      bpkp  = (f16*)(w + 41943040);            // 18,432,000 B
    f16*      hbufp = (f16*)(w + 60375040);            //    327,680 B
    float*    xzp   = (float*)(w + 60702720);          // 150*13*64*32*4 = 15,974,400 B
    unsigned* flagp = (unsigned*)(w + 76677120);       //        256 B
    int*      maxtp = (int*)(w + 76677376);

    hipLaunchKernelGGL(lstm_prep, dim3(1024), dim3(256), 0, stream,
                       x, Wf, Uf, Wb, Ub, len,
                       x16hp, x16lp, bpkp, (unsigned*)hbufp, flagp, maxtp, outp);

    hipLaunchKernelGGL(lstm_main, dim3(GRID_MAIN), dim3(256), 0, stream,
                       x16hp, x16lp, bpkp, hbufp, xzp, flagp, maxtp, len, bfv, bbv, outp);
}

// Round 9
// 6829.938 us; speedup vs baseline: 1.4414x; 1.0221x over previous
//
#include <hip/hip_runtime.h>
#include <hip/hip_fp16.h>
#include <cmath>

typedef _Float16 f16;
typedef _Float16 half8 __attribute__((ext_vector_type(8)));
typedef float f32x4 __attribute__((ext_vector_type(4)));

#define P_WG   75          // workgroups per direction (8 hidden units each)
#define GRID_MAIN (2*P_WG) // 150
#define G      12          // XZ lookahead distance
#define RING   13          // XZ ring slots (G+1)

#define X16_ELEMS  (64u*512u*320u)            // 10,485,760 f16 per plane
#define BPK_HALF   (2u*75u*2u*30u*64u*8u)     // 4,608,000 f16 (one term plane)
#define HBUF_F16   (2u*2u*64u*640u)           // dirs*bufs*rows*cols f16
#define HBUF_WORDS (HBUF_F16/2u)              // 81,920 u32
#define FLAG_WORDS 256u                       // 2 dirs x 128 u32 (75 flags + pad)

// ---------------- prep: rebuild all workspace state every launch ----------------
__global__ void lstm_prep(const float* __restrict__ x,
                          const float* __restrict__ Wf, const float* __restrict__ Uf,
                          const float* __restrict__ Wb, const float* __restrict__ Ub,
                          const int* __restrict__ len,
                          f16* __restrict__ x16h, f16* __restrict__ x16l,
                          f16* __restrict__ Bpk,
                          unsigned* __restrict__ hbw, unsigned* __restrict__ flags,
                          int* __restrict__ maxT, float* __restrict__ outp)
{
    const unsigned total = X16_ELEMS + BPK_HALF + HBUF_WORDS + FLAG_WORDS + 2u;
    for (unsigned e = blockIdx.x * blockDim.x + threadIdx.x; e < total;
         e += gridDim.x * blockDim.x) {
        if (e < X16_ELEMS) {
            unsigned k = e % 320u, r = e / 320u;   // r = b*512 + t
            float v = (k < 300u) ? x[r * 300u + k] : 0.0f;
            f16 hi = (f16)v;
            x16h[e] = hi;
            x16l[e] = (f16)((v - (float)hi) * 2048.0f);
        } else if (e < X16_ELEMS + BPK_HALF) {
            unsigned i = e - X16_ELEMS;
            // layout: [dir][p][term][nt][kt][lane][8]; fills term=0 and term=1
            unsigned j    = i & 7u,  r1 = i >> 3;
            unsigned lane = r1 & 63u, r2 = r1 >> 6;
            unsigned kt   = r2 % 30u, r3 = r2 / 30u;
            unsigned nt   = r3 & 1u,  r4 = r3 >> 1;
            unsigned p    = r4 % 75u, dw = r4 / 75u;
            unsigned k = kt * 32u + (lane >> 4) * 8u + j;     // B[k][n], k-octet per quad
            unsigned n = nt * 16u + (lane & 15u);             // n = gate*8 + jj
            unsigned c = (n >> 3) * 600u + p * 8u + (n & 7u); // source column in [0,2400)
            float v = 0.0f;
            if (k < 300u)                    v = (dw ? Wb : Wf)[k * 2400u + c];
            else if (k >= 320u && k < 920u)  v = (dw ? Ub : Uf)[(k - 320u) * 2400u + c];
            f16 hi = (f16)v;
            unsigned base = (((((dw * 75u + p) * 2u + 0u) * 2u + nt) * 30u + kt) * 64u + lane) * 8u + j;
            Bpk[base]          = hi;
            Bpk[base + 30720u] = (f16)((v - (float)hi) * 2048.0f); // lo pre-scaled by 2^11
        } else if (e < X16_ELEMS + BPK_HALF + HBUF_WORDS) {
            hbw[e - X16_ELEMS - BPK_HALF] = 0u;   // zero h ping-pong buffers, both dirs
        } else if (e < X16_ELEMS + BPK_HALF + HBUF_WORDS + FLAG_WORDS) {
            unsigned q = e - (X16_ELEMS + BPK_HALF + HBUF_WORDS);
            flags[q] = ((q & 127u) < 75u) ? 0u : 0xFFFFFFFFu;  // pads always satisfied
        } else {
            unsigned q = e - (X16_ELEMS + BPK_HALF + HBUF_WORDS + FLAG_WORDS);
            if (q == 0u) {
                int m = 1;
                for (int b = 0; b < 64; ++b) { int L = len[b]; m = (L > m) ? L : m; }
                *maxT = m;
            } else {
                outp[0] = 1000.0f;   // sentinel: lstm_main always overwrites out[0]
            }
        }
    }
}

// MALL-direct 16B load as 2x8B agent-scope atomic loads (bypass L1/L2 -> always fresh)
__device__ __forceinline__ half8 ld_h8_mall(const f16* p) {
    union { unsigned long long u[2]; half8 h; } x;
    x.u[0] = __hip_atomic_load((const unsigned long long*)p,     __ATOMIC_RELAXED, __HIP_MEMORY_SCOPE_AGENT);
    x.u[1] = __hip_atomic_load((const unsigned long long*)p + 1, __ATOMIC_RELAXED, __HIP_MEMORY_SCOPE_AGENT);
    return x.h;
}

// ---------------- main persistent recurrent kernel ----------------
__global__ __launch_bounds__(256, 1)
void lstm_main(const f16* __restrict__ x16h, const f16* __restrict__ x16l,
               const f16* __restrict__ Bpk,
               f16* __restrict__ hbuf, float* __restrict__ xz,
               unsigned* flags, const int* __restrict__ maxT,
               const int* __restrict__ len,
               const float* __restrict__ bfv, const float* __restrict__ bbv,
               float* __restrict__ out)
{
    __shared__ f32x4 obox[4][4][2][64];   // [src_wave][mt][nt][lane] : 32 KB merge buffer
    __shared__ f16 hstage[64][8];         // h transpose staging: 1 KB

    const int tid  = threadIdx.x;
    const int wave = tid >> 6, lane = tid & 63;
    const int quad = lane >> 4, l15 = lane & 15;
    const int dir  = blockIdx.x & 1, p = blockIdx.x >> 1;
    const int pc   = p * 8;
    const int wg   = blockIdx.x;

    // ---- resident h-part B fragments (hi term only): wave owns 5 kt in [10,30) ----
    const int s0 = (wave < 2) ? 3 : 2;    // kt = wave + 4*(s0+sp), sp=0..4
    half8 Bh[5][2];
#pragma unroll
    for (int sp = 0; sp < 5; ++sp) {
        int kt = wave + 4 * (s0 + sp);
#pragma unroll
        for (int nt = 0; nt < 2; ++nt)
            Bh[sp][nt] = *(const half8*)(Bpk +
                (((((unsigned)(dir * 75 + p) * 2 + 0) * 2 + nt) * 30 + kt) * 64 + lane) * 8);
    }
    const float* bias = dir ? bbv : bfv;
    const float b0 = bias[((l15 >> 3)    ) * 600 + pc + (l15 & 7)];  // gates i|f tile
    const float b1 = bias[((l15 >> 3) + 2) * 600 + pc + (l15 & 7)];  // gates g|o tile

    int Lm[4], Lr[4];
#pragma unroll
    for (int mt = 0; mt < 4; ++mt) Lm[mt] = len[mt * 16 + l15];        // initial-burst A rows
    const int Lw = len[wave * 16 + l15];                               // steady-burst A rows
#pragma unroll
    for (int r = 0; r < 4; ++r)   Lr[r]  = len[wave * 16 + quad * 4 + r]; // epilogue rows

    f16* hb0 = hbuf + dir * (2 * 64 * 640);
    unsigned* myflags = flags + dir * 128;
    float* myxz = xz + (size_t)wg * (RING * 64 * 32);
    float cst[4] = {0, 0, 0, 0}, sum[4] = {0, 0, 0, 0};
    const int T = *maxT;
    const unsigned bpk_base = (unsigned)(dir * 75 + p) * 4u * 30u * 512u;  // [dir][p] block, elems

    // ---- initial burst: fill XZ ring slots 0..G-1 (wave g-split, full K) ----
#pragma unroll
    for (int jc = 0; jc < 3; ++jc) {
        int g = wave * 3 + jc;
        int tt = (g < 512) ? g : 511;
        unsigned arow[4];
#pragma unroll
        for (int mt = 0; mt < 4; ++mt) {
            int tx = tt;
            if (dir) tx = (tt < Lm[mt]) ? (Lm[mt] - 1 - tt) : tt;  // reverse_sequence
            arow[mt] = ((unsigned)(mt * 16 + l15) * 512u + (unsigned)tx) * 320u + quad * 8;
        }
        f32x4 aH[4][2], aM[4][2];
#pragma unroll
        for (int mt = 0; mt < 4; ++mt)
#pragma unroll
            for (int nt = 0; nt < 2; ++nt) {
                aH[mt][nt] = f32x4{0.f, 0.f, 0.f, 0.f};
                aM[mt][nt] = f32x4{0.f, 0.f, 0.f, 0.f};
            }
#pragma unroll
        for (int kt = 0; kt < 10; ++kt) {
            const f16* bb = Bpk + bpk_base + kt * 512u + lane * 8;
            half8 B00 = *(const half8*)(bb);
            half8 B01 = *(const half8*)(bb + 15360);
            half8 B10 = *(const half8*)(bb + 30720);
            half8 B11 = *(const half8*)(bb + 46080);
#pragma unroll
            for (int mt = 0; mt < 4; ++mt) {
                half8 Ah = *(const half8*)(x16h + arow[mt] + kt * 32);
                half8 Al = *(const half8*)(x16l + arow[mt] + kt * 32);
                aH[mt][0] = __builtin_amdgcn_mfma_f32_16x16x32_f16(Ah, B00, aH[mt][0], 0, 0, 0);
                aM[mt][0] = __builtin_amdgcn_mfma_f32_16x16x32_f16(Ah, B10, aM[mt][0], 0, 0, 0);
                aM[mt][0] = __builtin_amdgcn_mfma_f32_16x16x32_f16(Al, B00, aM[mt][0], 0, 0, 0);
                aH[mt][1] = __builtin_amdgcn_mfma_f32_16x16x32_f16(Ah, B01, aH[mt][1], 0, 0, 0);
                aM[mt][1] = __builtin_amdgcn_mfma_f32_16x16x32_f16(Ah, B11, aM[mt][1], 0, 0, 0);
                aM[mt][1] = __builtin_amdgcn_mfma_f32_16x16x32_f16(Al, B01, aM[mt][1], 0, 0, 0);
            }
        }
#pragma unroll
        for (int mt = 0; mt < 4; ++mt)
#pragma unroll
            for (int r = 0; r < 4; ++r) {
                unsigned rowi = (unsigned)(g * 64 + mt * 16 + quad * 4 + r) * 32u;
                myxz[rowi + l15]      = aH[mt][0][r] + aM[mt][0][r] * (1.0f / 2048.0f) + b0;
                myxz[rowi + 16 + l15] = aH[mt][1][r] + aM[mt][1][r] * (1.0f / 2048.0f) + b1;
            }
    }
    __syncthreads();   // XZ slots 0..G-1 visible WG-wide (same CU: L1-coherent)

    for (int t = 0; t < T; ++t) {
        // ---- pipelined burst for step t+G (overlaps the notify chain) ----
        int tf = t + G;
        if (tf < T) {
            int tx = tf;
            if (dir) tx = (tf < Lw) ? (Lw - 1 - tf) : tf;
            unsigned arow = ((unsigned)(wave * 16 + l15) * 512u + (unsigned)tx) * 320u + quad * 8;
            f32x4 aH[2], aM[2];
            aH[0] = f32x4{0.f, 0.f, 0.f, 0.f}; aM[0] = f32x4{0.f, 0.f, 0.f, 0.f};
            aH[1] = f32x4{0.f, 0.f, 0.f, 0.f}; aM[1] = f32x4{0.f, 0.f, 0.f, 0.f};
#pragma unroll
            for (int kt = 0; kt < 10; ++kt) {
                const f16* bb = Bpk + bpk_base + kt * 512u + lane * 8;
                half8 B00 = *(const half8*)(bb);
                half8 B01 = *(const half8*)(bb + 15360);
                half8 B10 = *(const half8*)(bb + 30720);
                half8 B11 = *(const half8*)(bb + 46080);
                half8 Ah = *(const half8*)(x16h + arow + kt * 32);
                half8 Al = *(const half8*)(x16l + arow + kt * 32);
                aH[0] = __builtin_amdgcn_mfma_f32_16x16x32_f16(Ah, B00, aH[0], 0, 0, 0);
                aM[0] = __builtin_amdgcn_mfma_f32_16x16x32_f16(Ah, B10, aM[0], 0, 0, 0);
                aM[0] = __builtin_amdgcn_mfma_f32_16x16x32_f16(Al, B00, aM[0], 0, 0, 0);
                aH[1] = __builtin_amdgcn_mfma_f32_16x16x32_f16(Ah, B01, aH[1], 0, 0, 0);
                aM[1] = __builtin_amdgcn_mfma_f32_16x16x32_f16(Ah, B11, aM[1], 0, 0, 0);
                aM[1] = __builtin_amdgcn_mfma_f32_16x16x32_f16(Al, B01, aM[1], 0, 0, 0);
            }
            int slot = tf % RING;
#pragma unroll
            for (int r = 0; r < 4; ++r) {
                unsigned rowi = (unsigned)(slot * 64 + wave * 16 + quad * 4 + r) * 32u;
                myxz[rowi + l15]      = aH[0][r] + aM[0][r] * (1.0f / 2048.0f) + b0;
                myxz[rowi + 16 + l15] = aH[1][r] + aM[1][r] * (1.0f / 2048.0f) + b1;
            }
        }

        // ---- preload this step's XZ into registers (WG-local, L1-warm) ----
        float z0p[4], z1p[4];
        {
            int slot = t % RING;
            unsigned rbase = (unsigned)(slot * 64 + wave * 16 + quad * 4) * 32u;
#pragma unroll
            for (int r = 0; r < 4; ++r) {
                z0p[r] = myxz[rbase + r * 32 + l15];
                z1p[r] = myxz[rbase + r * 32 + 16 + l15];
            }
        }

        const f16* hcur = hb0 + (t & 1) * (64 * 640);
        f16*       hnxt = hb0 + ((t + 1) & 1) * (64 * 640);

        // ---- wait: wave 0 polls all 75 per-WG flags (independent lines, no RMW);
        //      40 lanes x u64; stability trait kept: only wave 0 polls ----
        if (t > 0 && wave == 0) {
            const unsigned tgt = (unsigned)t;
            const unsigned long long* f8 = (const unsigned long long*)myflags;
            for (;;) {
                unsigned long long v = ~0ull;
                if (lane < 40)
                    v = __hip_atomic_load(&f8[lane], __ATOMIC_RELAXED, __HIP_MEMORY_SCOPE_AGENT);
                bool bad = ((unsigned)v < tgt) || ((unsigned)(v >> 32) < tgt);
                if (!__any(bad)) break;
                __builtin_amdgcn_s_sleep(1);
            }
            __builtin_amdgcn_fence(__ATOMIC_ACQUIRE, "workgroup"); // order only; no cache inv
        }
        __syncthreads();   // B1: release all waves after the poll

        // ---- h-part: PREFETCH all 20 fragments (40 independent 8B MALL loads in
        //      flight, one drain) THEN run the 40 MFMAs — breaks load serialization ----
        half8 Ahh[5][4];
#pragma unroll
        for (int sp = 0; sp < 5; ++sp) {
            int kt = wave + 4 * (s0 + sp);
#pragma unroll
            for (int mt = 0; mt < 4; ++mt)
                Ahh[sp][mt] = ld_h8_mall(hcur + (unsigned)(mt * 16 + l15) * 640u + (kt * 32 - 320) + quad * 8);
        }
        f32x4 acc[4][2];
#pragma unroll
        for (int mt = 0; mt < 4; ++mt)
#pragma unroll
            for (int nt = 0; nt < 2; ++nt)
                acc[mt][nt] = f32x4{0.f, 0.f, 0.f, 0.f};
#pragma unroll
        for (int sp = 0; sp < 5; ++sp)
#pragma unroll
            for (int mt = 0; mt < 4; ++mt)
#pragma unroll
                for (int nt = 0; nt < 2; ++nt)
                    acc[mt][nt] = __builtin_amdgcn_mfma_f32_16x16x32_f16(Ahh[sp][mt], Bh[sp][nt], acc[mt][nt], 0, 0, 0);

        // ---- all-to-all K-merge through LDS ----
#pragma unroll
        for (int mt = 0; mt < 4; ++mt)
#pragma unroll
            for (int nt = 0; nt < 2; ++nt)
                obox[wave][mt][nt][lane] = acc[mt][nt];
        __syncthreads();   // B2: obox write -> read
        f32x4 z0 = obox[0][wave][0][lane] + obox[1][wave][0][lane]
                 + obox[2][wave][0][lane] + obox[3][wave][0][lane];
        f32x4 z1 = obox[0][wave][1][lane] + obox[1][wave][1][lane]
                 + obox[2][wave][1][lane] + obox[3][wave][1][lane];
        z0 += f32x4{z0p[0], z0p[1], z0p[2], z0p[3]};
        z1 += f32x4{z1p[0], z1p[1], z1p[2], z1p[3]};

        // ---- epilogue: this wave owns batch rows wave*16 .. wave*16+15 ----
#pragma unroll
        for (int r = 0; r < 4; ++r) {
            float zi = z0[r], zg = z1[r];
            float zf = __shfl_xor(z0[r], 8, 64);  // f gate lives 8 lanes over
            float zo = __shfl_xor(z1[r], 8, 64);
            if (l15 < 8) {
                float ig = 1.0f / (1.0f + __expf(-zi));
                float fg = 1.0f / (1.0f + __expf(-zf));
                float gg = tanhf(zg);
                float og = 1.0f / (1.0f + __expf(-zo));
                float c  = fg * cst[r] + ig * gg;
                cst[r] = c;
                float h = og * tanhf(c);
                if (t < Lr[r]) sum[r] += h;
                hstage[wave * 16 + quad * 4 + r][l15] = (f16)h;
            }
        }
        __syncthreads();   // B3: hstage ready; waves 1-3 run ahead to next burst

        // ---- wave 0 publishes h (1 KB) then RELEASE-stores its per-WG flag;
        //      the release store drains this wave's publish stores first ----
        if (wave == 0) {
            unsigned long long v0 = ((const unsigned long long*)&hstage[lane][0])[0];
            unsigned long long v1 = ((const unsigned long long*)&hstage[lane][0])[1];
            unsigned long long* dst = (unsigned long long*)(hnxt + (unsigned)lane * 640u + pc);
            __hip_atomic_store(dst,     v0, __ATOMIC_RELAXED, __HIP_MEMORY_SCOPE_AGENT);
            __hip_atomic_store(dst + 1, v1, __ATOMIC_RELAXED, __HIP_MEMORY_SCOPE_AGENT);
            if (lane == 0)
                __hip_atomic_store(myflags + p, (unsigned)(t + 1),
                                   __ATOMIC_RELEASE, __HIP_MEMORY_SCOPE_AGENT);
        }
    }

    // ---- output: masked mean over the sequence ----
    if (l15 < 8) {
#pragma unroll
        for (int r = 0; r < 4; ++r)
            out[(wave * 16 + quad * 4 + r) * 1200 + dir * 600 + pc + l15] =
                sum[r] * (1.0f / 512.0f);
    }
}

// ---------------- launcher ----------------
extern "C" void kernel_launch(void* const* d_in, const int* in_sizes, int n_in,
                              void* d_out, int out_size, void* d_ws, size_t ws_size,
                              hipStream_t stream) {
    const float* x   = (const float*)d_in[0];
    const int*   len = (const int*)  d_in[1];
    const float* Wf  = (const float*)d_in[3];
    const float* Uf  = (const float*)d_in[4];
    const float* bfv = (const float*)d_in[5];
    const float* Wb  = (const float*)d_in[6];
    const float* Ub  = (const float*)d_in[7];
    const float* bbv = (const float*)d_in[8];
    float* outp = (float*)d_out;

    char* w = (char*)d_ws;
    f16*      x16hp = (f16*)w;                         // 20,971,520 B
    f16*      x16lp = (f16*)(w + 20971520);            // 20,971,520 B
    f16*      bpkp  = (f16*)(w + 41943040);            // 18,432,000 B
    f16*      hbufp = (f16*)(w + 60375040);            //    327,680 B
    float*    xzp   = (float*)(w + 60702720);          // 150*13*64*32*4 = 15,974,400 B
    unsigned* flagp = (unsigned*)(w + 76677120);       //      1,024 B
    int*      maxtp = (int*)(w + 76678144);

    hipLaunchKernelGGL(lstm_prep, dim3(1024), dim3(256), 0, stream,
                       x, Wf, Uf, Wb, Ub, len,
                       x16hp, x16lp, bpkp, (unsigned*)hbufp, flagp, maxtp, outp);

    hipLaunchKernelGGL(lstm_main, dim3(GRID_MAIN), dim3(256), 0, stream,
                       x16hp, x16lp, bpkp, hbufp, xzp, flagp, maxtp, len, bfv, bbv, outp);
}